// Round 2
// baseline (606.528 us; speedup 1.0000x reference)
//
#include <hip/hip_runtime.h>

// Problem: x [B=256,1,512,512] f32; weights [512,4,1]; biases [512,1].
// out[b,i] = relu( dot(ring_means(b,i,0..3), weights[i,:,0]) + biases[i] )
// ring index per corner for pixel (r,c):
//   tl: max(r,c)  tr: max(r,511-c)  bl: max(511-r,c)  br: max(511-r,511-c)
//
// One streaming pass accumulating ring SUMS into per-(b,chunk) partial bins
// (no global atomics, no memset); kernel 2 folds partials + mean + linear +
// bias + relu.

#define HH 512
#define WW 512
#define NRING 512
#define NB (4 * NRING)   // bins per image: [corner][ring]

// ---------------- Kernel 1: ring sums ----------------
// grid: B*8 blocks of 256 threads (4 waves). Block = (image b, 64-row chunk).
// Wave w owns rows chunk*64 + w*16 .. +15, processed as 2 batches of 8 rows.
// Per batch: issue all 16 float4 loads first (MLP!), then masked accumulate:
//  - ring determined by row  -> per-row wave-reduced sums (32 values/batch)
//  - ring determined by col  -> per-lane REGISTER bins, flushed once at end
template<bool PARTIALS>
__global__ __launch_bounds__(256, 4)
void ring_sum_kernel(const float* __restrict__ x, float* __restrict__ ws) {
    __shared__ float bins[NB];   // [corner][ring], 8 KiB
    const int tid  = threadIdx.x;
    const int lane = tid & 63;
    const int wave = tid >> 6;
    const int b     = blockIdx.x >> 3;
    const int chunk = blockIdx.x & 7;

    for (int t = tid; t < NB; t += 256) bins[t] = 0.f;
    __syncthreads();

    float vTL[8] = {0,0,0,0,0,0,0,0};
    float vTR[8] = {0,0,0,0,0,0,0,0};
    float vBL[8] = {0,0,0,0,0,0,0,0};
    float vBR[8] = {0,0,0,0,0,0,0,0};

    const float4* img = (const float4*)x + (size_t)b * (HH * WW / 4);
    const int cA = 4 * lane;        // columns cA..cA+3
    const int cB = 256 + 4 * lane;  // columns cB..cB+3

    const int rbase = chunk * 64 + wave * 16;
    const bool top = (rbase < 256);   // wave-uniform (chunk-aligned)

    for (int batch = 0; batch < 2; ++batch) {
        const int r0 = rbase + batch * 8;

        // ---- issue all 16 loads up front ----
        float4 A[8], Bv[8];
        #pragma unroll
        for (int j = 0; j < 8; ++j) {
            const float4* rowp = img + (size_t)(r0 + j) * (WW / 4);
            A[j]  = rowp[lane];
            Bv[j] = rowp[64 + lane];
        }
        __builtin_amdgcn_sched_barrier(0);

        // ---- masked accumulate ----
        float u[32];   // [row j][corner tl,tr,bl,br]
        #pragma unroll
        for (int j = 0; j < 8; ++j) {
            const int r = r0 + j;
            const int s = 511 - r;
            float uTL = 0.f, uTR = 0.f, uBL = 0.f, uBR = 0.f;
            if (top) {
                #pragma unroll
                for (int e = 0; e < 4; ++e) {       // group A: c < 256
                    float v = (&A[j].x)[e]; int c = cA + e;
                    uBL += v;
                    vTR[e] += v;
                    float sel  = (c <= r) ? v : 0.f; uTL += sel;  vTL[e] += v - sel;
                    float sel2 = (c >= r) ? v : 0.f; uBR += sel2; vBR[e] += v - sel2;
                }
                #pragma unroll
                for (int e = 0; e < 4; ++e) {       // group B: c >= 256
                    float v = (&Bv[j].x)[e]; int c = cB + e;
                    uBR += v;
                    vTL[4 + e] += v;
                    float sel  = (c >= s) ? v : 0.f; uTR += sel;  vTR[4 + e] += v - sel;
                    float sel2 = (c <= s) ? v : 0.f; uBL += sel2; vBL[4 + e] += v - sel2;
                }
            } else {
                #pragma unroll
                for (int e = 0; e < 4; ++e) {       // group A
                    float v = (&A[j].x)[e]; int c = cA + e;
                    uTL += v;
                    vBR[e] += v;
                    float sel  = (c >= s) ? v : 0.f; uTR += sel;  vTR[e] += v - sel;
                    float sel2 = (c <= s) ? v : 0.f; uBL += sel2; vBL[e] += v - sel2;
                }
                #pragma unroll
                for (int e = 0; e < 4; ++e) {       // group B
                    float v = (&Bv[j].x)[e]; int c = cB + e;
                    uTR += v;
                    vBL[4 + e] += v;
                    float sel  = (c <= r) ? v : 0.f; uTL += sel;  vTL[4 + e] += v - sel;
                    float sel2 = (c >= r) ? v : 0.f; uBR += sel2; vBR[4 + e] += v - sel2;
                }
            }
            u[j * 4 + 0] = uTL; u[j * 4 + 1] = uTR;
            u[j * 4 + 2] = uBL; u[j * 4 + 3] = uBR;
        }

        // ---- interleaved wave reduce of 32 row-uniform sums ----
        #pragma unroll
        for (int off = 32; off > 0; off >>= 1) {
            #pragma unroll
            for (int q = 0; q < 32; ++q) u[q] += __shfl_down(u[q], off);
        }
        if (lane == 0) {
            #pragma unroll
            for (int j = 0; j < 8; ++j) {
                const int r = r0 + j, s = 511 - r;
                atomicAdd(&bins[0 * NRING + r], u[j * 4 + 0]);
                atomicAdd(&bins[1 * NRING + r], u[j * 4 + 1]);
                atomicAdd(&bins[2 * NRING + s], u[j * 4 + 2]);
                atomicAdd(&bins[3 * NRING + s], u[j * 4 + 3]);
            }
        }
    }

    // flush per-lane register bins (ring depends only on owned column c)
    #pragma unroll
    for (int e = 0; e < 8; ++e) {
        int c = (e < 4) ? (cA + e) : (cB + e - 4);
        atomicAdd(&bins[0 * NRING + c],         vTL[e]);
        atomicAdd(&bins[1 * NRING + (511 - c)], vTR[e]);
        atomicAdd(&bins[2 * NRING + c],         vBL[e]);
        atomicAdd(&bins[3 * NRING + (511 - c)], vBR[e]);
    }
    __syncthreads();

    if (PARTIALS) {
        // plain coalesced store of this block's private bins
        float* outp = ws + ((size_t)b * 8 + chunk) * NB;
        for (int t = tid; t < NB; t += 256) outp[t] = bins[t];
    } else {
        float* outp = ws + (size_t)b * NB;
        for (int t = tid; t < NB; t += 256) atomicAdd(&outp[t], bins[t]);
    }
}

// ------------- Kernel 2: fold partials + mean + linear + bias + relu -------
__global__ __launch_bounds__(512)
void linear_kernel(const float* __restrict__ ws, const float* __restrict__ wts,
                   const float* __restrict__ bias, float* __restrict__ out,
                   int nparts) {
    const int b = blockIdx.x;
    const int i = threadIdx.x;   // ring index
    const float* base = ws + (size_t)b * nparts * NB;
    float s0 = 0.f, s1 = 0.f, s2 = 0.f, s3 = 0.f;
    for (int p = 0; p < nparts; ++p) {
        const float* pb = base + (size_t)p * NB;
        s0 += pb[0 * NRING + i];
        s1 += pb[1 * NRING + i];
        s2 += pb[2 * NRING + i];
        s3 += pb[3 * NRING + i];
    }
    float4 w  = ((const float4*)wts)[i];          // weights[i][0..3][0]
    float inv = 1.0f / (float)(2 * i + 1);
    float val = (s0 * w.x + s1 * w.y + s2 * w.z + s3 * w.w) * inv + bias[i];
    out[b * NRING + i] = fmaxf(val, 0.0f);
}

extern "C" void kernel_launch(void* const* d_in, const int* in_sizes, int n_in,
                              void* d_out, int out_size, void* d_ws, size_t ws_size,
                              hipStream_t stream) {
    const float* x    = (const float*)d_in[0];
    const float* wts  = (const float*)d_in[1];
    const float* bias = (const float*)d_in[2];
    float* out = (float*)d_out;

    const int B = in_sizes[0] / (HH * WW);   // 256
    float* ws = (float*)d_ws;

    const size_t need = (size_t)B * 8 * NB * sizeof(float);   // 16 MiB
    if (ws_size >= need) {
        ring_sum_kernel<true><<<dim3(B * 8), dim3(256), 0, stream>>>(x, ws);
        linear_kernel<<<dim3(B), dim3(512), 0, stream>>>(ws, wts, bias, out, 8);
    } else {
        hipMemsetAsync(ws, 0, (size_t)B * NB * sizeof(float), stream);
        ring_sum_kernel<false><<<dim3(B * 8), dim3(256), 0, stream>>>(x, ws);
        linear_kernel<<<dim3(B), dim3(512), 0, stream>>>(ws, wts, bias, out, 1);
    }
}

// Round 3
// 407.359 us; speedup vs baseline: 1.4889x; 1.4889x over previous
//
#include <hip/hip_runtime.h>

// Problem: x [B=256,1,512,512] f32; weights [512,4,1]; biases [512,1].
// out[b,i] = relu( dot(ring_means(b,i,0..3), weights[i,:,0]) + biases[i] )
// ring index per corner for pixel (r,c):
//   tl: max(r,c)  tr: max(r,511-c)  bl: max(511-r,c)  br: max(511-r,511-c)
//
// One streaming pass accumulating ring SUMS into per-(b,chunk) partial bins
// (plain stores, no global atomics); kernel 2 folds partials + mean + linear
// + bias + relu.
//
// R3 lesson: batch-of-8 + launch_bounds(256,4) spilled (VGPR cap 64/128 vs
// ~140 live) -> 571MB scratch writes. Now: batch-of-4 with 1-ahead prefetch,
// fully unrolled (static indexing), no min-wave bound.

#define HH 512
#define WW 512
#define NRING 512
#define NB (4 * NRING)   // bins per image: [corner][ring]

// ---------------- Kernel 1: ring sums ----------------
// grid: B*8 blocks of 256 threads (4 waves). Block = (image b, 64-row chunk).
// Wave w owns rows chunk*64 + w*16 .. +15, as 4 pipelined batches of 4 rows.
template<bool PARTIALS>
__global__ __launch_bounds__(256)
void ring_sum_kernel(const float* __restrict__ x, float* __restrict__ ws) {
    __shared__ float bins[NB];   // [corner][ring], 8 KiB
    const int tid  = threadIdx.x;
    const int lane = tid & 63;
    const int wave = tid >> 6;
    const int b     = blockIdx.x >> 3;
    const int chunk = blockIdx.x & 7;

    for (int t = tid; t < NB; t += 256) bins[t] = 0.f;
    __syncthreads();

    float vTL[8] = {0,0,0,0,0,0,0,0};
    float vTR[8] = {0,0,0,0,0,0,0,0};
    float vBL[8] = {0,0,0,0,0,0,0,0};
    float vBR[8] = {0,0,0,0,0,0,0,0};

    const float4* img = (const float4*)x + (size_t)b * (HH * WW / 4);
    const int cA = 4 * lane;        // columns cA..cA+3
    const int cB = 256 + 4 * lane;  // columns cB..cB+3

    const int rbase = chunk * 64 + wave * 16;
    const bool top = (rbase < 256);   // wave-uniform (16-row span can't cross)

    float4 A[2][4], Bv[2][4];        // double-buffered row data (64 VGPRs)

    // prime batch 0
    #pragma unroll
    for (int j = 0; j < 4; ++j) {
        const float4* rowp = img + (size_t)(rbase + j) * (WW / 4);
        A[0][j]  = rowp[lane];
        Bv[0][j] = rowp[64 + lane];
    }

    #pragma unroll
    for (int batch = 0; batch < 4; ++batch) {
        const int cur = batch & 1, nxt = cur ^ 1;
        // prefetch next batch
        if (batch < 3) {
            #pragma unroll
            for (int j = 0; j < 4; ++j) {
                const float4* rowp = img + (size_t)(rbase + (batch + 1) * 4 + j) * (WW / 4);
                A[nxt][j]  = rowp[lane];
                Bv[nxt][j] = rowp[64 + lane];
            }
        }
        __builtin_amdgcn_sched_barrier(0);   // pin prefetch before compute

        const int r0 = rbase + batch * 4;
        float u[16];   // [row j][corner tl,tr,bl,br]
        #pragma unroll
        for (int j = 0; j < 4; ++j) {
            const int r = r0 + j;
            const int s = 511 - r;
            float uTL = 0.f, uTR = 0.f, uBL = 0.f, uBR = 0.f;
            if (top) {
                #pragma unroll
                for (int e = 0; e < 4; ++e) {       // group A: c < 256
                    float v = (&A[cur][j].x)[e]; int c = cA + e;
                    uBL += v;
                    vTR[e] += v;
                    float sel  = (c <= r) ? v : 0.f; uTL += sel;  vTL[e] += v - sel;
                    float sel2 = (c >= r) ? v : 0.f; uBR += sel2; vBR[e] += v - sel2;
                }
                #pragma unroll
                for (int e = 0; e < 4; ++e) {       // group B: c >= 256
                    float v = (&Bv[cur][j].x)[e]; int c = cB + e;
                    uBR += v;
                    vTL[4 + e] += v;
                    float sel  = (c >= s) ? v : 0.f; uTR += sel;  vTR[4 + e] += v - sel;
                    float sel2 = (c <= s) ? v : 0.f; uBL += sel2; vBL[4 + e] += v - sel2;
                }
            } else {
                #pragma unroll
                for (int e = 0; e < 4; ++e) {       // group A
                    float v = (&A[cur][j].x)[e]; int c = cA + e;
                    uTL += v;
                    vBR[e] += v;
                    float sel  = (c >= s) ? v : 0.f; uTR += sel;  vTR[e] += v - sel;
                    float sel2 = (c <= s) ? v : 0.f; uBL += sel2; vBL[e] += v - sel2;
                }
                #pragma unroll
                for (int e = 0; e < 4; ++e) {       // group B
                    float v = (&Bv[cur][j].x)[e]; int c = cB + e;
                    uTR += v;
                    vBL[4 + e] += v;
                    float sel  = (c <= r) ? v : 0.f; uTL += sel;  vTL[4 + e] += v - sel;
                    float sel2 = (c >= r) ? v : 0.f; uBR += sel2; vBR[4 + e] += v - sel2;
                }
            }
            u[j * 4 + 0] = uTL; u[j * 4 + 1] = uTR;
            u[j * 4 + 2] = uBL; u[j * 4 + 3] = uBR;
        }

        // interleaved wave reduce of 16 row-uniform sums
        #pragma unroll
        for (int off = 32; off > 0; off >>= 1) {
            #pragma unroll
            for (int q = 0; q < 16; ++q) u[q] += __shfl_down(u[q], off);
        }
        if (lane == 0) {
            #pragma unroll
            for (int j = 0; j < 4; ++j) {
                const int r = r0 + j, s = 511 - r;
                atomicAdd(&bins[0 * NRING + r], u[j * 4 + 0]);
                atomicAdd(&bins[1 * NRING + r], u[j * 4 + 1]);
                atomicAdd(&bins[2 * NRING + s], u[j * 4 + 2]);
                atomicAdd(&bins[3 * NRING + s], u[j * 4 + 3]);
            }
        }
    }

    // flush per-lane register bins (ring depends only on owned column c)
    #pragma unroll
    for (int e = 0; e < 8; ++e) {
        int c = (e < 4) ? (cA + e) : (cB + e - 4);
        atomicAdd(&bins[0 * NRING + c],         vTL[e]);
        atomicAdd(&bins[1 * NRING + (511 - c)], vTR[e]);
        atomicAdd(&bins[2 * NRING + c],         vBL[e]);
        atomicAdd(&bins[3 * NRING + (511 - c)], vBR[e]);
    }
    __syncthreads();

    if (PARTIALS) {
        // plain coalesced store of this block's private bins
        float* outp = ws + ((size_t)b * 8 + chunk) * NB;
        for (int t = tid; t < NB; t += 256) outp[t] = bins[t];
    } else {
        float* outp = ws + (size_t)b * NB;
        for (int t = tid; t < NB; t += 256) atomicAdd(&outp[t], bins[t]);
    }
}

// ------------- Kernel 2: fold partials + mean + linear + bias + relu -------
__global__ __launch_bounds__(512)
void linear_kernel(const float* __restrict__ ws, const float* __restrict__ wts,
                   const float* __restrict__ bias, float* __restrict__ out,
                   int nparts) {
    const int b = blockIdx.x;
    const int i = threadIdx.x;   // ring index
    const float* base = ws + (size_t)b * nparts * NB;
    float s0 = 0.f, s1 = 0.f, s2 = 0.f, s3 = 0.f;
    for (int p = 0; p < nparts; ++p) {
        const float* pb = base + (size_t)p * NB;
        s0 += pb[0 * NRING + i];
        s1 += pb[1 * NRING + i];
        s2 += pb[2 * NRING + i];
        s3 += pb[3 * NRING + i];
    }
    float4 w  = ((const float4*)wts)[i];          // weights[i][0..3][0]
    float inv = 1.0f / (float)(2 * i + 1);
    float val = (s0 * w.x + s1 * w.y + s2 * w.z + s3 * w.w) * inv + bias[i];
    out[b * NRING + i] = fmaxf(val, 0.0f);
}

extern "C" void kernel_launch(void* const* d_in, const int* in_sizes, int n_in,
                              void* d_out, int out_size, void* d_ws, size_t ws_size,
                              hipStream_t stream) {
    const float* x    = (const float*)d_in[0];
    const float* wts  = (const float*)d_in[1];
    const float* bias = (const float*)d_in[2];
    float* out = (float*)d_out;

    const int B = in_sizes[0] / (HH * WW);   // 256
    float* ws = (float*)d_ws;

    const size_t need = (size_t)B * 8 * NB * sizeof(float);   // 16 MiB
    if (ws_size >= need) {
        ring_sum_kernel<true><<<dim3(B * 8), dim3(256), 0, stream>>>(x, ws);
        linear_kernel<<<dim3(B), dim3(512), 0, stream>>>(ws, wts, bias, out, 8);
    } else {
        hipMemsetAsync(ws, 0, (size_t)B * NB * sizeof(float), stream);
        ring_sum_kernel<false><<<dim3(B * 8), dim3(256), 0, stream>>>(x, ws);
        linear_kernel<<<dim3(B), dim3(512), 0, stream>>>(ws, wts, bias, out, 1);
    }
}